// Round 15
// baseline (188.066 us; speedup 1.0000x reference)
//
#include <hip/hip_runtime.h>

typedef _Float16 half8 __attribute__((ext_vector_type(8)));
typedef float floatx4 __attribute__((ext_vector_type(4)));

#define NB 64
#define NN 2048
#define ND 128
#define NT 1024
#define NC 16           // n-rows per chunk
#define NCHUNKS 128     // NN / NC (full sweep per block)
#define NIV 64          // intervals of 2 chunks

// exp2-domain constants: alpha^2 = 0.5*log2(e); scaling W,targets by alpha
// makes (alpha*d)^2 sums directly usable as log2 exponents.
#define ALPHA 0.84932184f
#define INV_ALPHA 1.17741002f
#define LP2_MAJOR (-1.7369655941662063f)   // log2(0.9/3)
#define LP2_MINOR (-12.321928094887362f)   // log2(0.1/512)

// bare v_exp_f32 (input already in log2 units, always <= 0 here)
__device__ __forceinline__ float fexp2(float x) {
  float r;
  asm("v_exp_f32 %0, %1" : "=v"(r) : "v"(x));
  return r;
}

// keep-alive pin (r4-proven form: once, immediately after the loads)
#define PIN8(x) asm volatile("" : "+v"(x))

// DPP row_shr add step for 16-lane inclusive scan (zero-fill at row edge)
template <int CTRL>
__device__ __forceinline__ float dppshr_add(float x) {
  int i = __builtin_bit_cast(int, x);
  int s = __builtin_amdgcn_update_dpp(0, i, CTRL, 0xF, 0xF, true);
  return x + __builtin_bit_cast(float, s);
}
// inclusive scan over l15 within each 16-lane row
__device__ __forceinline__ float scan16(float x) {
  x = dppshr_add<0x111>(x);   // row_shr:1
  x = dppshr_add<0x112>(x);   // row_shr:2
  x = dppshr_add<0x114>(x);   // row_shr:4
  x = dppshr_add<0x118>(x);   // row_shr:8
  return x;
}
// broadcast row-lane-15 value to all 16 lanes of the row
__device__ __forceinline__ float bcast15(float x) {
  int i = __builtin_bit_cast(int, x);
  i = __builtin_amdgcn_ds_swizzle(i, 0x1F0);
  return __builtin_bit_cast(float, i);
}

// ---- prep: W_all (f32, [D][T]) -> alpha-scaled t-major f16 hi/lo [t][d] ------
__global__ void k_prep(const float* __restrict__ W, const float* __restrict__ Wm,
                       _Float16* __restrict__ Wph, _Float16* __restrict__ Wpl) {
  int idx = blockIdx.x * 256 + threadIdx.x;      // 131072 = 1024*128
  int t = idx >> 7, d = idx & 127;
  float x = (t < 512) ? W[d * 512 + t] : Wm[d * 512 + (t - 512)];
  x *= ALPHA;
  _Float16 h = (_Float16)x;
  _Float16 l = (_Float16)(x - (float)h);
  Wph[idx] = h;
  Wpl[idx] = l;
}

// ---- prep: data -> per-chunk packed [chunk: hi 2048h | lo 2048h] -------------
__global__ void k_prep_data(const float* __restrict__ data,
                            _Float16* __restrict__ Apk) {
  int idx = blockIdx.x * 256 + threadIdx.x;      // 2,097,152 threads
  int l = idx & 63, kk = (idx >> 6) & 3, ch = (idx >> 8) & 127, b = idx >> 15;
  int row = ch * 16 + (l & 15);
  int dcol = kk * 32 + (l >> 4) * 8;
  const float* src = data + ((size_t)b * NN + row) * ND + dcol;
  floatx4 a0 = *(const floatx4*)src;
  floatx4 a1 = *(const floatx4*)(src + 4);
  half8 h, lo;
#pragma unroll
  for (int j = 0; j < 4; ++j) {
    h[j] = (_Float16)a0[j];
    lo[j] = (_Float16)(a0[j] - (float)h[j]);
    h[4 + j] = (_Float16)a1[j];
    lo[4 + j] = (_Float16)(a1[j] - (float)h[4 + j]);
  }
  size_t o = ((size_t)(b * 128 + ch)) * 4096 + kk * 512 + l * 8;
  *(half8*)(Apk + o) = h;            // hi half of chunk block
  *(half8*)(Apk + o + 2048) = lo;    // lo half of chunk block
}

// ---- fused single pass: block = (b, tq); 8 waves x 16 t; streams all 2048 n --
// 4 waves/SIMD occupancy; EPI pipelined one interval behind the GEMM.
__global__ __launch_bounds__(512, 4)
void k_fused(const _Float16* __restrict__ Apk, const float* __restrict__ targets,
             const _Float16* __restrict__ Wph, const _Float16* __restrict__ Wpl,
             floatx4* __restrict__ part) {
  int bid = blockIdx.x;
  // XCD-affinity: all 8 tq-partners of one b share bid%8 -> same XCD L2
  int xcd = bid & 7, rest = bid >> 3;
  int tq = rest & 7, b = (rest >> 3) * 8 + xcd;
  int tid = threadIdx.x;
  int w = tid >> 6, l = tid & 63;
  int l15 = l & 15, lhi = l >> 4;
  int tbase = tq * 128 + w * 16;

  // W fragments for this wave's 16 t: 32 VGPRs
  half8 wh[4], wl[4];
#pragma unroll
  for (int kk = 0; kk < 4; ++kk) {
    int off = (tbase + l15) * 128 + kk * 32 + lhi * 8;
    wh[kk] = *(const half8*)(Wph + off);
    wl[kk] = *(const half8*)(Wpl + off);
  }
#pragma unroll
  for (int kk = 0; kk < 4; ++kk) { PIN8(wh[kk]); PIN8(wl[kk]); }

  float prior2 = (tq < 4) ? LP2_MAJOR : LP2_MINOR;   // t<512 <=> tq<4
  // pmr = prior2 - running n-prefix (per t = lhi*4+r), maintained directly
  floatx4 pmr = {prior2, prior2, prior2, prior2};

  const _Float16* abase = Apk + (size_t)b * 128 * 4096;
  const float* tgp = targets + (size_t)b * NN + l15;
  size_t pbase = (size_t)b * NN * 8 + tq;

  __shared__ _Float16 Abuf[2][8192];        // [buf][2-chunk pair] 32 KB
  __shared__ floatx4 sm4[8][4][17];         // [wave][slot][n] {m,s1,s2,-} 8.7 KB

  int t8 = tid * 8;                         // staging slice (one b128 per chunk)

#define GEMM3(ACC, AH, AL)                                                     \
  do {                                                                         \
    floatx4 hh = {0.f, 0.f, 0.f, 0.f};                                         \
    floatx4 hl = {0.f, 0.f, 0.f, 0.f};                                         \
    floatx4 lh = {0.f, 0.f, 0.f, 0.f};                                         \
    _Pragma("unroll")                                                          \
    for (int kk = 0; kk < 4; ++kk) {                                           \
      hh = __builtin_amdgcn_mfma_f32_16x16x32_f16(wh[kk], AH[kk], hh, 0, 0, 0);\
      hl = __builtin_amdgcn_mfma_f32_16x16x32_f16(wh[kk], AL[kk], hl, 0, 0, 0);\
      lh = __builtin_amdgcn_mfma_f32_16x16x32_f16(wl[kk], AH[kk], lh, 0, 0, 0);\
    }                                                                          \
    ACC = (hh + hl) + lh;                                                      \
  } while (0)

  // EPI: one chunk; wave-level (16 t) partial per n via xor16/32 fold
#define EPI(A, SLOT, TGS)                                             \
  do {                                                                \
    floatx4 tg4 = {(TGS), (TGS), (TGS), (TGS)};                       \
    floatx4 d = tg4 - (A);                                            \
    floatx4 q = d * d;                                                \
    floatx4 i0;                                                       \
    _Pragma("unroll")                                                 \
    for (int r = 0; r < 4; ++r) i0[r] = scan16(q[r]);                 \
    floatx4 lp = pmr + (q - i0);                                      \
    _Pragma("unroll")                                                 \
    for (int r = 0; r < 4; ++r) pmr[r] -= bcast15(i0[r]);             \
    float m = fmaxf(fmaxf(lp[0], lp[1]), fmaxf(lp[2], lp[3]));        \
    m = fmaxf(m, __shfl_xor(m, 16));                                  \
    m = fmaxf(m, __shfl_xor(m, 32));                                  \
    floatx4 m4 = {m, m, m, m};                                        \
    floatx4 x = lp - m4;                                              \
    floatx4 e;                                                        \
    _Pragma("unroll")                                                 \
    for (int r = 0; r < 4; ++r) e[r] = fexp2(x[r]);                   \
    float s1 = (e[0] + e[1]) + (e[2] + e[3]);                         \
    float s2 = e[0] * (A)[0];                                         \
    s2 = fmaf(e[1], (A)[1], s2);                                      \
    s2 = fmaf(e[2], (A)[2], s2);                                      \
    s2 = fmaf(e[3], (A)[3], s2);                                      \
    s1 += __shfl_xor(s1, 16); s1 += __shfl_xor(s1, 32);               \
    s2 += __shfl_xor(s2, 16); s2 += __shfl_xor(s2, 32);               \
    if (l < 16) {                                                     \
      floatx4 outv;                                                   \
      outv[0] = m; outv[1] = s1; outv[2] = s2; outv[3] = 0.f;         \
      sm4[w][SLOT][l] = outv;                                         \
    }                                                                 \
  } while (0)

  // merge 8 wave-partials per n, 4 chunks at a time
#define MERGE(BASECH)                                                 \
  do {                                                                \
    if (tid < 64) {                                                   \
      int c4 = tid >> 4, row = tid & 15;                              \
      float M = -3.4e38f;                                             \
      _Pragma("unroll")                                               \
      for (int wv = 0; wv < 8; ++wv)                                  \
        M = fmaxf(M, sm4[wv][c4][row][0]);                            \
      float S1 = 0.f, S2 = 0.f;                                       \
      _Pragma("unroll")                                               \
      for (int wv = 0; wv < 8; ++wv) {                                \
        floatx4 vv = sm4[wv][c4][row];                                \
        float e = fexp2(vv[0] - M);                                   \
        S1 = fmaf(vv[1], e, S1);                                      \
        S2 = fmaf(vv[2], e, S2);                                      \
      }                                                               \
      floatx4 v;                                                      \
      v[0] = M; v[1] = S1; v[2] = S2; v[3] = 0.f;                     \
      part[pbase + (size_t)(((BASECH) + c4) * 16 + row) * 8] = v;     \
    }                                                                 \
  } while (0)

#define LOADFRAGS(OFF)                                                \
  _Pragma("unroll")                                                   \
  for (int kk = 0; kk < 4; ++kk) {                                    \
    ah[kk] = *(const half8*)&Abuf[cur][(OFF) + kk * 512 + l * 8];     \
    al[kk] = *(const half8*)&Abuf[cur][(OFF) + 2048 + kk * 512 + l * 8]; \
  }

  // prologue: stage interval 0 (chunks 0,1); prefetch interval 1 into regs
  half8 s0 = *(const half8*)(abase + t8);
  half8 s1_ = *(const half8*)(abase + 4096 + t8);
  *(half8*)&Abuf[0][t8] = s0;
  *(half8*)&Abuf[0][4096 + t8] = s1_;
  s0 = *(const half8*)(abase + 2 * 4096 + t8);
  s1_ = *(const half8*)(abase + 3 * 4096 + t8);
  __syncthreads();

  floatx4 pA, pB;                 // previous interval's accumulators
  float ptgA, ptgB;

  // iv = 0: GEMM chunks 0,1 -> prev; stage interval 1; prefetch interval 2
  {
    int cur = 0;
    half8 ah[4], al[4];
    LOADFRAGS(0);
    GEMM3(pA, ah, al);
    LOADFRAGS(4096);
    GEMM3(pB, ah, al);
    ptgA = tgp[0] * ALPHA;
    ptgB = tgp[16] * ALPHA;
    *(half8*)&Abuf[1][t8] = s0;
    *(half8*)&Abuf[1][4096 + t8] = s1_;
    const _Float16* pp = abase + 2 * 8192 + t8;
    s0 = *(const half8*)pp;
    s1_ = *(const half8*)(pp + 4096);
    __syncthreads();
    tgp += 32;
  }

  for (int iv = 1; iv < NIV; ++iv) {
    int cur = iv & 1;
    half8 ah[4], al[4];
    floatx4 aA, aB;
    LOADFRAGS(0);
    GEMM3(aA, ah, al);
    LOADFRAGS(4096);
    GEMM3(aB, ah, al);
    float tgA = tgp[0] * ALPHA;
    float tgB = tgp[16] * ALPHA;

    // stage next interval (loaded an interval ago); prefetch iv+2
    *(half8*)&Abuf[cur ^ 1][t8] = s0;
    *(half8*)&Abuf[cur ^ 1][4096 + t8] = s1_;
    {
      int pf = iv + 2 > 63 ? 63 : iv + 2;
      const _Float16* pp = abase + (size_t)pf * 8192 + t8;
      s0 = *(const half8*)pp;
      s1_ = *(const half8*)(pp + 4096);
    }

    // epilogue of PREVIOUS interval's chunks (independent of this GEMM)
    EPI(pA, ((2 * iv - 2) & 3), ptgA);
    EPI(pB, ((2 * iv - 1) & 3), ptgB);

    if (!(iv & 1)) {                 // even iv: slots 0..3 = chunks 2iv-4..2iv-1
      __syncthreads();
      MERGE(2 * iv - 4);
    }
    __syncthreads();

    pA = aA; pB = aB;
    ptgA = tgA; ptgB = tgB;
    tgp += 32;
  }

  // tail: chunks 126,127 epilogue + final merge (chunks 124..127)
  EPI(pA, 2, ptgA);
  EPI(pB, 3, ptgB);
  __syncthreads();
  MERGE(124);

#undef EPI
#undef GEMM3
#undef MERGE
#undef LOADFRAGS
}

// ---- combine 8 tq-partials per (b,n) -----------------------------------------
__global__ void k_combine(const floatx4* __restrict__ part, float* __restrict__ out) {
  int idx = blockIdx.x * 256 + threadIdx.x;   // 131072 = NB*NN
  const floatx4* p = part + (size_t)idx * 8;
  floatx4 v[8];
  float M = -3.4e38f;
#pragma unroll
  for (int j = 0; j < 8; ++j) { v[j] = p[j]; M = fmaxf(M, v[j][0]); }
  float s1 = 0.f, s2 = 0.f;
#pragma unroll
  for (int j = 0; j < 8; ++j) {
    float e = fexp2(v[j][0] - M);
    s1 += v[j][1] * e;
    s2 += v[j][2] * e;
  }
  out[idx] = s2 / s1 * INV_ALPHA;   // undo alpha scale on XW values
}

extern "C" void kernel_launch(void* const* d_in, const int* in_sizes, int n_in,
                              void* d_out, int out_size, void* d_ws, size_t ws_size,
                              hipStream_t stream) {
  const float* data    = (const float*)d_in[0];
  const float* targets = (const float*)d_in[1];
  const float* W       = (const float*)d_in[2];
  const float* Wm      = (const float*)d_in[3];
  float* out = (float*)d_out;

  char* ws = (char*)d_ws;
  const size_t MB = 1u << 20;
  _Float16* Wph  = (_Float16*)ws;                          // 256 KB
  _Float16* Wpl  = (_Float16*)(ws + 256 * 1024);           // 256 KB
  _Float16* Apk  = (_Float16*)(ws + 512 * 1024);           // 64 MB packed hi/lo
  floatx4* part  = (floatx4*)(ws + 512 * 1024 + 64 * MB);  // 16 MB

  k_prep<<<512, 256, 0, stream>>>(W, Wm, Wph, Wpl);
  k_prep_data<<<8192, 256, 0, stream>>>(data, Apk);
  k_fused<<<NB * 8, 512, 0, stream>>>(Apk, targets, Wph, Wpl, part);
  k_combine<<<(NB * NN) / 256, 256, 0, stream>>>(part, out);
}

// Round 16
// 168.946 us; speedup vs baseline: 1.1132x; 1.1132x over previous
//
#include <hip/hip_runtime.h>

typedef _Float16 half8 __attribute__((ext_vector_type(8)));
typedef float floatx4 __attribute__((ext_vector_type(4)));

#define NB 64
#define NN 2048
#define ND 128
#define NT 1024
#define NC 16           // n-rows per chunk
#define NCHUNKS 128     // NN / NC (full sweep per block)
#define NIV 64          // intervals of 2 chunks
#define CHB 6144        // bytes per chunk block: [ah 4096 | al8 2048]
#define IVB 12288       // bytes per 2-chunk interval

// exp2-domain constants: alpha^2 = 0.5*log2(e); scaling W,targets by alpha
// makes (alpha*d)^2 sums directly usable as log2 exponents.
#define ALPHA 0.84932184f
#define INV_ALPHA 1.17741002f
#define LP2_MAJOR (-1.7369655941662063f)   // log2(0.9/3)
#define LP2_MINOR (-12.321928094887362f)   // log2(0.1/512)
#define AL_SCALE 65536.0f
#define AL_UNSCALE 0x1p-16f

// bare v_exp_f32 (input already in log2 units, always <= 0 here)
__device__ __forceinline__ float fexp2(float x) {
  float r;
  asm("v_exp_f32 %0, %1" : "=v"(r) : "v"(x));
  return r;
}

// keep-alive pin (r4-proven form: once, immediately after the loads)
#define PIN8(x) asm volatile("" : "+v"(x))

// DPP row_shr add step for 16-lane inclusive scan (zero-fill at row edge)
template <int CTRL>
__device__ __forceinline__ float dppshr_add(float x) {
  int i = __builtin_bit_cast(int, x);
  int s = __builtin_amdgcn_update_dpp(0, i, CTRL, 0xF, 0xF, true);
  return x + __builtin_bit_cast(float, s);
}
// inclusive scan over l15 within each 16-lane row
__device__ __forceinline__ float scan16(float x) {
  x = dppshr_add<0x111>(x);   // row_shr:1
  x = dppshr_add<0x112>(x);   // row_shr:2
  x = dppshr_add<0x114>(x);   // row_shr:4
  x = dppshr_add<0x118>(x);   // row_shr:8
  return x;
}
// broadcast row-lane-15 value to all 16 lanes of the row
__device__ __forceinline__ float bcast15(float x) {
  int i = __builtin_bit_cast(int, x);
  i = __builtin_amdgcn_ds_swizzle(i, 0x1F0);
  return __builtin_bit_cast(float, i);
}

// ---- prep: W_all -> alpha-scaled t-major f16 hi/lo + fp8(e4m3) full ----------
__global__ void k_prep(const float* __restrict__ W, const float* __restrict__ Wm,
                       _Float16* __restrict__ Wph, _Float16* __restrict__ Wpl,
                       unsigned char* __restrict__ Wp8) {
  int idx = blockIdx.x * 256 + threadIdx.x;      // 131072 = 1024*128
  int t = idx >> 7, d = idx & 127;
  float x = (t < 512) ? W[d * 512 + t] : Wm[d * 512 + (t - 512)];
  x *= ALPHA;
  _Float16 h = (_Float16)x;
  _Float16 l = (_Float16)(x - (float)h);
  Wph[idx] = h;
  Wpl[idx] = l;
  int pk = __builtin_amdgcn_cvt_pk_fp8_f32(x, x, 0, false);
  Wp8[idx] = (unsigned char)(pk & 0xff);
}

// ---- prep: data -> per-chunk packed [ah f16 4096B | al8 fp8*2^16 2048B] ------
__global__ void k_prep_data(const float* __restrict__ data,
                            char* __restrict__ Apk) {
  int idx = blockIdx.x * 256 + threadIdx.x;      // 2,097,152 threads
  int l = idx & 63, kk = (idx >> 6) & 3, ch = (idx >> 8) & 127, b = idx >> 15;
  int row = ch * 16 + (l & 15);
  int dcol = kk * 32 + (l >> 4) * 8;
  const float* src = data + ((size_t)b * NN + row) * ND + dcol;
  floatx4 a0 = *(const floatx4*)src;
  floatx4 a1 = *(const floatx4*)(src + 4);
  half8 h;
  float alf[8];
#pragma unroll
  for (int j = 0; j < 4; ++j) {
    h[j] = (_Float16)a0[j];
    alf[j] = (a0[j] - (float)h[j]) * AL_SCALE;
    h[4 + j] = (_Float16)a1[j];
    alf[4 + j] = (a1[j] - (float)h[4 + j]) * AL_SCALE;
  }
  int w0 = __builtin_amdgcn_cvt_pk_fp8_f32(alf[0], alf[1], 0, false);
  w0 = __builtin_amdgcn_cvt_pk_fp8_f32(alf[2], alf[3], w0, true);
  int w1 = __builtin_amdgcn_cvt_pk_fp8_f32(alf[4], alf[5], 0, false);
  w1 = __builtin_amdgcn_cvt_pk_fp8_f32(alf[6], alf[7], w1, true);
  size_t cb = (size_t)(b * 128 + ch) * CHB;
  *(half8*)(Apk + cb + kk * 1024 + l * 16) = h;
  int2 pk2 = {w0, w1};
  *(int2*)(Apk + cb + 4096 + kk * 512 + l * 8) = pk2;
}

// ---- fused single pass: block = (b, tq); 4 waves x 32 t; streams all 2048 n --
// GEMM terms: ah*wh + ah*wl (f16) + al8*w8 (fp8, 2^-16-scaled correction).
__global__ __launch_bounds__(256, 2)
void k_fused(const char* __restrict__ Apk, const float* __restrict__ targets,
             const _Float16* __restrict__ Wph, const _Float16* __restrict__ Wpl,
             const unsigned char* __restrict__ Wp8,
             floatx4* __restrict__ part) {
  int bid = blockIdx.x;
  // XCD-affinity: all 8 tq-partners of one b share bid%8 -> same XCD L2
  int xcd = bid & 7, rest = bid >> 3;
  int tq = rest & 7, b = (rest >> 3) * 8 + xcd;
  int tid = threadIdx.x;
  int w = tid >> 6, l = tid & 63;
  int l15 = l & 15, lhi = l >> 4;
  int wavebase = tq * 128 + w * 32;

  // W fragments for this wave's 32 t (2 tiles): f16 hi/lo + fp8 full
  half8 wh[2][4], wl[2][4];
  long w8q[2][4];
#pragma unroll
  for (int tt = 0; tt < 2; ++tt)
#pragma unroll
    for (int kk = 0; kk < 4; ++kk) {
      int off = (wavebase + tt * 16 + l15) * 128 + kk * 32 + lhi * 8;
      wh[tt][kk] = *(const half8*)(Wph + off);
      wl[tt][kk] = *(const half8*)(Wpl + off);
      w8q[tt][kk] = *(const long*)(Wp8 + off);
    }
#pragma unroll
  for (int tt = 0; tt < 2; ++tt)
#pragma unroll
    for (int kk = 0; kk < 4; ++kk) {
      PIN8(wh[tt][kk]); PIN8(wl[tt][kk]); PIN8(w8q[tt][kk]);
    }

  float prior2 = (tq < 4) ? LP2_MAJOR : LP2_MINOR;   // t<512 <=> tq<4
  float run[2][4] = {{0.f, 0.f, 0.f, 0.f}, {0.f, 0.f, 0.f, 0.f}};

  const char* abase = Apk + (size_t)b * 128 * CHB;
  const float* tgp = targets + (size_t)b * NN + l15;
  size_t pbase = (size_t)b * NN * 8 + tq;

  __shared__ char Abuf[2][IVB];             // [buf][2-chunk pair] 24 KB
  __shared__ float sm[4][4][65][3];         // lane-indexed, conflict-free 12.5 KB

  int t16 = tid * 16;                       // staging slice base (bytes)

#define GEMM3(ACC, TT, AH, A8)                                                      \
  do {                                                                              \
    floatx4 hh = {0.f, 0.f, 0.f, 0.f};                                              \
    floatx4 hl = {0.f, 0.f, 0.f, 0.f};                                              \
    floatx4 l8 = {0.f, 0.f, 0.f, 0.f};                                              \
    _Pragma("unroll")                                                               \
    for (int kk = 0; kk < 4; ++kk) {                                                \
      hh = __builtin_amdgcn_mfma_f32_16x16x32_f16(wh[TT][kk], AH[kk], hh, 0, 0, 0); \
      hl = __builtin_amdgcn_mfma_f32_16x16x32_f16(wl[TT][kk], AH[kk], hl, 0, 0, 0); \
      l8 = __builtin_amdgcn_mfma_f32_16x16x32_fp8_fp8(w8q[TT][kk], A8[kk], l8, 0, 0, 0); \
    }                                                                               \
    ACC = (hh + hl);                                                                \
    ACC += l8 * AL_UNSCALE;                                                         \
  } while (0)

  // EPI over both t-tiles of one chunk; per-LANE partial (8 t's) into sm[w][slot][l]
#define EPI(ACC0, ACC1, SLOT, TGOFF)                                  \
  do {                                                                \
    float tgs = tgp[TGOFF] * ALPHA;                                   \
    float q[2][4], inc[2][4], lp[2][4];                               \
    _Pragma("unroll")                                                 \
    for (int r = 0; r < 4; ++r) {                                     \
      float d0 = tgs - ACC0[r], d1 = tgs - ACC1[r];                   \
      q[0][r] = d0 * d0; q[1][r] = d1 * d1;                           \
    }                                                                 \
    _Pragma("unroll")                                                 \
    for (int tt = 0; tt < 2; ++tt)                                    \
      _Pragma("unroll")                                               \
      for (int r = 0; r < 4; ++r) inc[tt][r] = scan16(q[tt][r]);      \
    _Pragma("unroll")                                                 \
    for (int tt = 0; tt < 2; ++tt)                                    \
      _Pragma("unroll")                                               \
      for (int r = 0; r < 4; ++r) {                                   \
        lp[tt][r] = (prior2 - run[tt][r]) + (q[tt][r] - inc[tt][r]);  \
        run[tt][r] += bcast15(inc[tt][r]);                            \
      }                                                               \
    float m = fmaxf(fmaxf(fmaxf(lp[0][0], lp[0][1]),                  \
                          fmaxf(lp[0][2], lp[0][3])),                 \
                    fmaxf(fmaxf(lp[1][0], lp[1][1]),                  \
                          fmaxf(lp[1][2], lp[1][3])));                \
    float s1 = 0.f, s2 = 0.f;                                         \
    _Pragma("unroll")                                                 \
    for (int r = 0; r < 4; ++r) {                                     \
      float e0 = fexp2(lp[0][r] - m), e1 = fexp2(lp[1][r] - m);       \
      s1 += e0 + e1;                                                  \
      s2 = fmaf(e0, ACC0[r], s2);                                     \
      s2 = fmaf(e1, ACC1[r], s2);                                     \
    }                                                                 \
    sm[w][SLOT][l][0] = m;                                            \
    sm[w][SLOT][l][1] = s1;                                           \
    sm[w][SLOT][l][2] = s2;                                           \
  } while (0)

#define LOADFRAGS(C)                                                  \
  _Pragma("unroll")                                                   \
  for (int kk = 0; kk < 4; ++kk) {                                    \
    ah[kk] = *(const half8*)&Abuf[cur][(C) * CHB + kk * 1024 + l * 16];        \
    a8[kk] = *(const long*)&Abuf[cur][(C) * CHB + 4096 + kk * 512 + l * 8];    \
  }

  // prologue: stage interval 0 (chunks 0,1); prefetch interval 1 into regs
  half8 s0 = *(const half8*)(abase + t16);
  half8 s1_ = *(const half8*)(abase + 4096 + t16);
  half8 s2_ = *(const half8*)(abase + 8192 + t16);
  *(half8*)&Abuf[0][t16] = s0;
  *(half8*)&Abuf[0][4096 + t16] = s1_;
  *(half8*)&Abuf[0][8192 + t16] = s2_;
  s0 = *(const half8*)(abase + IVB + t16);
  s1_ = *(const half8*)(abase + IVB + 4096 + t16);
  s2_ = *(const half8*)(abase + IVB + 8192 + t16);
  __syncthreads();

  for (int iv = 0; iv < NIV; ++iv) {
    int cur = iv & 1;
    // chunk A = 2*iv
    half8 ah[4];
    long a8[4];
    LOADFRAGS(0);
    floatx4 accA0, accA1;
    GEMM3(accA0, 0, ah, a8);
    GEMM3(accA1, 1, ah, a8);
    // chunk B = 2*iv+1
    LOADFRAGS(1);
    floatx4 accB0, accB1;
    GEMM3(accB0, 0, ah, a8);
    GEMM3(accB1, 1, ah, a8);

    // stage next interval (loaded an interval ago); prefetch iv+2
    *(half8*)&Abuf[cur ^ 1][t16] = s0;
    *(half8*)&Abuf[cur ^ 1][4096 + t16] = s1_;
    *(half8*)&Abuf[cur ^ 1][8192 + t16] = s2_;
    {
      int pf = iv + 2 > 63 ? 63 : iv + 2;
      const char* pp = abase + (size_t)pf * IVB + t16;
      s0 = *(const half8*)pp;
      s1_ = *(const half8*)(pp + 4096);
      s2_ = *(const half8*)(pp + 8192);
    }

    EPI(accA0, accA1, ((2 * iv) & 3), 0);
    EPI(accB0, accB1, ((2 * iv + 1) & 3), 16);

    if (iv & 1) {                    // 4 chunks complete -> merge + emit
      __syncthreads();
      if (tid < 64) {
        int c4 = tid >> 4, row = tid & 15;
        // fold 16 per-lane partials: 4 waves x 4 lhi-groups (l = g*16 + row)
        float M = -3.4e38f;
#pragma unroll
        for (int wv = 0; wv < 4; ++wv)
#pragma unroll
          for (int g = 0; g < 4; ++g)
            M = fmaxf(M, sm[wv][c4][g * 16 + row][0]);
        float S1 = 0.f, S2 = 0.f;
#pragma unroll
        for (int wv = 0; wv < 4; ++wv)
#pragma unroll
          for (int g = 0; g < 4; ++g) {
            float e = fexp2(sm[wv][c4][g * 16 + row][0] - M);
            S1 = fmaf(sm[wv][c4][g * 16 + row][1], e, S1);
            S2 = fmaf(sm[wv][c4][g * 16 + row][2], e, S2);
          }
        floatx4 v;
        v[0] = M; v[1] = S1; v[2] = S2; v[3] = 0.f;
        part[pbase + (size_t)((2 * iv - 2 + c4) * 16 + row) * 8] = v;
      }
    }
    __syncthreads();
    tgp += 32;
  }
#undef EPI
#undef GEMM3
#undef LOADFRAGS
}

// ---- combine 8 tq-partials per (b,n) -----------------------------------------
__global__ void k_combine(const floatx4* __restrict__ part, float* __restrict__ out) {
  int idx = blockIdx.x * 256 + threadIdx.x;   // 131072 = NB*NN
  const floatx4* p = part + (size_t)idx * 8;
  floatx4 v[8];
  float M = -3.4e38f;
#pragma unroll
  for (int j = 0; j < 8; ++j) { v[j] = p[j]; M = fmaxf(M, v[j][0]); }
  float s1 = 0.f, s2 = 0.f;
#pragma unroll
  for (int j = 0; j < 8; ++j) {
    float e = fexp2(v[j][0] - M);
    s1 += v[j][1] * e;
    s2 += v[j][2] * e;
  }
  out[idx] = s2 / s1 * INV_ALPHA;   // undo alpha scale on XW values
}

extern "C" void kernel_launch(void* const* d_in, const int* in_sizes, int n_in,
                              void* d_out, int out_size, void* d_ws, size_t ws_size,
                              hipStream_t stream) {
  const float* data    = (const float*)d_in[0];
  const float* targets = (const float*)d_in[1];
  const float* W       = (const float*)d_in[2];
  const float* Wm      = (const float*)d_in[3];
  float* out = (float*)d_out;

  char* ws = (char*)d_ws;
  const size_t MB = 1u << 20;
  _Float16* Wph      = (_Float16*)ws;                      // 256 KB
  _Float16* Wpl      = (_Float16*)(ws + 256 * 1024);       // 256 KB
  unsigned char* Wp8 = (unsigned char*)(ws + 512 * 1024);  // 128 KB
  char* Apk          = (char*)(ws + 1 * MB);               // 48 MB packed
  floatx4* part      = (floatx4*)(ws + 49 * MB);           // 16 MB

  k_prep<<<512, 256, 0, stream>>>(W, Wm, Wph, Wpl, Wp8);
  k_prep_data<<<8192, 256, 0, stream>>>(data, Apk);
  k_fused<<<NB * 8, 256, 0, stream>>>(Apk, targets, Wph, Wpl, Wp8, part);
  k_combine<<<(NB * NN) / 256, 256, 0, stream>>>(part, out);
}